// Round 7
// baseline (122.411 us; speedup 1.0000x reference)
//
#include <hip/hip_runtime.h>

typedef __bf16 bf16_t;
typedef bf16_t bf16x8 __attribute__((ext_vector_type(8)));
typedef bf16_t bf16x4 __attribute__((ext_vector_type(4)));
typedef float f32x4 __attribute__((ext_vector_type(4)));

#define SEQLEN 2048
#define EMB 1024
#define NHEADS 16
#define N3 3072
#define NBATCH 2
#define NEG_INF (-__builtin_inff())
#define SC2 0.18033688011112042f   // 0.125 * log2(e): softmax in exp2 domain

// async global->LDS, 16B per lane. LDS base must be wave-uniform.
__device__ __forceinline__ void async16(bf16_t* lds, const bf16_t* g) {
    __builtin_amdgcn_global_load_lds(
        (const __attribute__((address_space(1))) void*)g,
        (__attribute__((address_space(3))) void*)lds, 16, 0, 0);
}

// ---------------------------------------------------------------------------
// Combined weight transpose + fp32->bf16: W_qkv (48 col-blocks, Q cols
// pre-scaled by SC2) and W_out (16 col-blocks) in one launch.
// ---------------------------------------------------------------------------
__global__ __launch_bounds__(256) void transpose_weights(
    const float* __restrict__ Wqkv, const float* __restrict__ Wout,
    bf16_t* __restrict__ Wqkv_t, bf16_t* __restrict__ Wout_t)
{
    __shared__ float tile[64][65];
    int bx = blockIdx.x;
    const int k0 = blockIdx.y * 64;
    const float* W; bf16_t* Wt; int N; float s;
    if (bx < 48) { W = Wqkv; Wt = Wqkv_t; N = N3;  s = (bx * 64 < EMB) ? SC2 : 1.0f; }
    else         { bx -= 48; W = Wout; Wt = Wout_t; N = EMB; s = 1.0f; }
    const int n0 = bx * 64;
    const int t = threadIdx.x;
    const int nl = t & 63, k4 = t >> 6;
#pragma unroll
    for (int i = 0; i < 16; ++i) {
        int kk = k4 + i * 4;
        tile[kk][nl] = W[(size_t)(k0 + kk) * N + n0 + nl];
    }
    __syncthreads();
    const int kl = t & 63, n4 = t >> 6;
#pragma unroll
    for (int i = 0; i < 16; ++i) {
        int nn = n4 + i * 4;
        Wt[(size_t)(n0 + nn) * EMB + k0 + kl] = (bf16_t)(tile[kl][nn] * s);
    }
}

// ---------------------------------------------------------------------------
// fp32 -> bf16 convert (X pre-convert), 8 elems/thread
// ---------------------------------------------------------------------------
__global__ __launch_bounds__(256) void cvt_f32_bf16(
    const float* __restrict__ in, bf16_t* __restrict__ out, int n)
{
    const int i = (blockIdx.x * 256 + threadIdx.x) * 8;
    if (i >= n) return;
    float4 a = *(const float4*)&in[i];
    float4 b = *(const float4*)&in[i + 4];
    bf16_t v[8];
    v[0] = (bf16_t)a.x; v[1] = (bf16_t)a.y; v[2] = (bf16_t)a.z; v[3] = (bf16_t)a.w;
    v[4] = (bf16_t)b.x; v[5] = (bf16_t)b.y; v[6] = (bf16_t)b.z; v[7] = (bf16_t)b.w;
    *(float4*)&out[i] = *(float4*)&v[0];
}

// ---------------------------------------------------------------------------
// GEMM 256x256 8-phase (T2+T3+T4+T5): C = A[M][K](bf16) @ Bt[N][K]^T + bias.
// 512 thr = 8 waves (2M x 4N), BK=64, 2 K-tiles/iter, LDS 128 KiB dbuf.
// Staging: global_load_lds w/ pre-swizzled source; ds_read w/ XOR-after-add
// swizzle byte ^= ((row&7)<<4). Counted vmcnt(4) at phases 4/8 only.
// Quadrant order frees each LDS half before its prefetch overwrite issues:
//   ph1 (m0-3,n0-1): read A0(8) B01(4); prefetch t+1 B0 -> buf1
//   ph2 (m4-7,n0-1): read A1(8);        prefetch t+1 B1 -> buf1
//   ph3 (m4-7,n2-3): read B23(4);       prefetch t+2 A0 -> buf0 (A free after ph2)
//   ph4 (m0-3,n2-3): reuse regs;        prefetch t+2 A1; vmcnt(4) [t+1 landed]
//   ph5-8: mirror on buf1, prefetch t+2 B0/B1 -> buf0, t+3 A0/A1 -> buf1
// ---------------------------------------------------------------------------
#define MFMA16(MLO, NLO, AF, BF)                                              \
    _Pragma("unroll")                                                         \
    for (int m_ = 0; m_ < 4; ++m_) {                                          \
        _Pragma("unroll")                                                     \
        for (int n_ = 0; n_ < 2; ++n_) {                                      \
            acc[(MLO) + m_][(NLO) + n_] =                                     \
                __builtin_amdgcn_mfma_f32_16x16x32_bf16(                      \
                    AF[m_ * 2], BF[n_ * 2],                                   \
                    acc[(MLO) + m_][(NLO) + n_], 0, 0, 0);                    \
            acc[(MLO) + m_][(NLO) + n_] =                                     \
                __builtin_amdgcn_mfma_f32_16x16x32_bf16(                      \
                    AF[m_ * 2 + 1], BF[n_ * 2 + 1],                           \
                    acc[(MLO) + m_][(NLO) + n_], 0, 0, 0);                    \
        }                                                                     \
    }
#define BAR() __builtin_amdgcn_s_barrier()
#define VMC(N)                                                                \
    do { asm volatile("s_waitcnt vmcnt(" #N ")" ::: "memory");                \
         __builtin_amdgcn_sched_barrier(0); } while (0)

template<bool OUT_BF16, bool V_SPLIT>
__global__ __launch_bounds__(512, 2) void gemm_8ph_kernel(
    const bf16_t* __restrict__ A, const bf16_t* __restrict__ Bt,
    const float* __restrict__ bias, void* __restrict__ Cp,
    bf16_t* __restrict__ vt, int scale_q, int Ndim, int Kdim)
{
    __shared__ bf16_t As[2][2][8192];   // [buf][half][128*64]
    __shared__ bf16_t Bs[2][2][8192];
    const int nb = Ndim >> 8;
    const int cpx = gridDim.x >> 3;
    const int bid = (blockIdx.x & 7) * cpx + (blockIdx.x >> 3);
    const int bx = bid % nb, by = bid / nb;
    const int r0 = by << 8, c0 = bx << 8;
    const int t = threadIdx.x, lane = t & 63, w = t >> 6;
    const int wm = w >> 2, wn = w & 3;
    const int lr = lane & 15, lg = lane >> 4;

    // ds_read lane bases (byte, within one [128][64] half): XOR after adds
    const int rb0 = (lr * 128 + lg * 16) ^ ((lr & 7) << 4);
    const int rb1 = (lr * 128 + 64 + lg * 16) ^ ((lr & 7) << 4);

    // gload lane source: row = w*16 + i*8 + (l>>3); colbyte pre-swizzled
    const int gr = (w << 4) + (lane >> 3);
    const int gcb = (((lane & 7) ^ (lane >> 3)) << 4);
    const size_t Kb = (size_t)Kdim * 2;
    const char* gAp = (const char*)A + (size_t)(r0 + gr) * Kb + gcb;
    const char* gBp = (const char*)Bt + (size_t)(c0 + gr) * Kb + gcb;

    auto stgA = [&](int buf, int half, int kt) {
        const char* s = gAp + (size_t)(half << 7) * Kb + kt * 128;
        bf16_t* d = &As[buf][half][w << 10];
        async16(d, (const bf16_t*)s);
        async16(d + 512, (const bf16_t*)(s + (Kb << 3)));
    };
    auto stgB = [&](int buf, int half, int kt) {
        const char* s = gBp + (size_t)(half << 7) * Kb + kt * 128;
        bf16_t* d = &Bs[buf][half][w << 10];
        async16(d, (const bf16_t*)s);
        async16(d + 512, (const bf16_t*)(s + (Kb << 3)));
    };
    auto ldA = [&](bf16x8* dst, int buf, int mlo) {
        const char* base = (const char*)&As[buf][wm][0];
#pragma unroll
        for (int m_ = 0; m_ < 4; ++m_) {
            dst[m_ * 2]     = *(const bf16x8*)(base + (mlo + m_) * 2048 + rb0);
            dst[m_ * 2 + 1] = *(const bf16x8*)(base + (mlo + m_) * 2048 + rb1);
        }
    };
    auto ldB = [&](bf16x8* dst, int buf, int nlo) {
        const char* base = (const char*)&Bs[buf][wn >> 1][0] + ((wn & 1) << 13);
#pragma unroll
        for (int n_ = 0; n_ < 2; ++n_) {
            dst[n_ * 2]     = *(const bf16x8*)(base + (nlo + n_) * 2048 + rb0);
            dst[n_ * 2 + 1] = *(const bf16x8*)(base + (nlo + n_) * 2048 + rb1);
        }
    };

    f32x4 acc[8][4] = {};
    bf16x8 a0[8], a1[8], bf[4];

    // prologue: t0 all 4 halves -> buf0; t1 A0,A1 -> buf1
    stgA(0, 0, 0); stgA(0, 1, 0); stgB(0, 0, 0); stgB(0, 1, 0);
    stgA(1, 0, 1); stgA(1, 1, 1);
    VMC(4);                 // t0 fully landed (4 newest = t1 A-halves)
    BAR();

    const int KT = Kdim >> 6;
    const int iters = KT >> 1;
    for (int k = 0; k < iters; ++k) {
        const int tt = 2 * k;
        const bool nx2 = (tt + 2 < KT), nx3 = (tt + 3 < KT);
        const bool last = (k == iters - 1);
        // ---- phase 1: buf0 (m0-3, n0-1)
        ldA(a0, 0, 0); ldB(bf, 0, 0);
        stgB(1, 0, tt + 1);
        BAR();
        __builtin_amdgcn_s_setprio(1); MFMA16(0, 0, a0, bf); __builtin_amdgcn_s_setprio(0);
        BAR();
        // ---- phase 2: (m4-7, n0-1)
        ldA(a1, 0, 4);
        stgB(1, 1, tt + 1);
        BAR();
        __builtin_amdgcn_s_setprio(1); MFMA16(4, 0, a1, bf); __builtin_amdgcn_s_setprio(0);
        BAR();
        // ---- phase 3: (m4-7, n2-3)
        ldB(bf, 0, 2);
        if (nx2) stgA(0, 0, tt + 2);
        BAR();
        __builtin_amdgcn_s_setprio(1); MFMA16(4, 2, a1, bf); __builtin_amdgcn_s_setprio(0);
        BAR();
        // ---- phase 4: (m0-3, n2-3), then counted wait for t+1
        if (nx2) stgA(0, 1, tt + 2);
        BAR();
        __builtin_amdgcn_s_setprio(1); MFMA16(0, 2, a0, bf); __builtin_amdgcn_s_setprio(0);
        if (last) { VMC(0); } else { VMC(4); }
        BAR();
        // ---- phase 5: buf1 (m0-3, n0-1)
        ldA(a0, 1, 0); ldB(bf, 1, 0);
        if (nx2) stgB(0, 0, tt + 2);
        BAR();
        __builtin_amdgcn_s_setprio(1); MFMA16(0, 0, a0, bf); __builtin_amdgcn_s_setprio(0);
        BAR();
        // ---- phase 6: (m4-7, n0-1)
        ldA(a1, 1, 4);
        if (nx2) stgB(0, 1, tt + 2);
        BAR();
        __builtin_amdgcn_s_setprio(1); MFMA16(4, 0, a1, bf); __builtin_amdgcn_s_setprio(0);
        BAR();
        // ---- phase 7: (m4-7, n2-3)
        ldB(bf, 1, 2);
        if (nx3) stgA(1, 0, tt + 3);
        BAR();
        __builtin_amdgcn_s_setprio(1); MFMA16(4, 2, a1, bf); __builtin_amdgcn_s_setprio(0);
        BAR();
        // ---- phase 8: (m0-3, n2-3), counted wait for t+2
        if (nx3) stgA(1, 1, tt + 3);
        BAR();
        __builtin_amdgcn_s_setprio(1); MFMA16(0, 2, a0, bf); __builtin_amdgcn_s_setprio(0);
        if (last) { VMC(0); } else { VMC(4); }
        BAR();
    }

    // epilogue
    const bool vmode = V_SPLIT && (c0 >= 2 * EMB);
#pragma unroll
    for (int m = 0; m < 8; ++m) {
#pragma unroll
        for (int n = 0; n < 4; ++n) {
            const int col = c0 + wn * 64 + n * 16 + lr;
            float bval = bias[col];
            if (scale_q && col < EMB) bval *= SC2;
            if (vmode) {
                const int h = (col - 2 * EMB) >> 6, dd = col & 63;
                const int bb = r0 >> 11;
                const int sbase = (r0 & (SEQLEN - 1)) + wm * 128 + m * 16 + lg * 4;
                bf16x4 pk;
#pragma unroll
                for (int j = 0; j < 4; ++j) pk[j] = (bf16_t)(acc[m][n][j] + bval);
                *(bf16x4*)&vt[(size_t)((bb * 16 + h) * 64 + dd) * SEQLEN + sbase] = pk;
            } else {
#pragma unroll
                for (int j = 0; j < 4; ++j) {
                    const int row = r0 + wm * 128 + m * 16 + lg * 4 + j;
                    const float v = acc[m][n][j] + bval;
                    if (OUT_BF16)
                        ((bf16_t*)Cp)[(size_t)row * Ndim + col] = (bf16_t)v;
                    else
                        ((float*)Cp)[(size_t)row * Ndim + col] = v;
                }
            }
        }
    }
}

// ---------------------------------------------------------------------------
// GEMM (m97 structure, 128x128): used for GEMM2 (N=1024 -> 256 blocks).
// ---------------------------------------------------------------------------
template<bool OUT_BF16>
__global__ __launch_bounds__(256) void gemm_bt_kernel(
    const bf16_t* __restrict__ A, const bf16_t* __restrict__ Bt,
    const float* __restrict__ bias, void* __restrict__ Cp,
    int Mdim, int Ndim, int Kdim)
{
    __shared__ bf16_t As[128 * 32];
    __shared__ bf16_t Bs[128 * 32];
    const int nb = Ndim >> 7;
    const int cpx = gridDim.x >> 3;
    const int bid = (blockIdx.x & 7) * cpx + (blockIdx.x >> 3);
    const int bx = bid % nb, by = bid / nb;
    const int r0 = by << 7, c0 = bx << 7;
    const int t = threadIdx.x, lane = t & 63;
    const int wid = t >> 6;
    const int wm = wid >> 1, wn = wid & 1;
    const int lr = lane & 15, lg = lane >> 4;

    const int glrow = wid * 32 + (lane >> 2);
    const int glcol = (lane & 3) << 3;
    bf16_t* ldsA = &As[wid * 1024];
    bf16_t* ldsB = &Bs[wid * 1024];
    const bf16_t* gA = &A[(size_t)(r0 + glrow) * Kdim + glcol];
    const bf16_t* gB = &Bt[(size_t)(c0 + glrow) * Kdim + glcol];
    const size_t rowstep = (size_t)16 * Kdim;

    f32x4 acc[4][4] = {};
    const int KT = Kdim >> 5;
    for (int kt = 0; kt < KT; ++kt) {
        const int k0 = kt << 5;
        async16(ldsA,       gA + k0);
        async16(ldsA + 512, gA + k0 + rowstep);
        async16(ldsB,       gB + k0);
        async16(ldsB + 512, gB + k0 + rowstep);
        __syncthreads();
        bf16x8 af[4], bfm[4];
#pragma unroll
        for (int m = 0; m < 4; ++m)
            af[m] = *(const bf16x8*)&As[(wm * 64 + m * 16 + lr) * 32 + lg * 8];
#pragma unroll
        for (int n = 0; n < 4; ++n)
            bfm[n] = *(const bf16x8*)&Bs[(wn * 64 + n * 16 + lr) * 32 + lg * 8];
#pragma unroll
        for (int m = 0; m < 4; ++m)
#pragma unroll
            for (int n = 0; n < 4; ++n)
                acc[m][n] = __builtin_amdgcn_mfma_f32_16x16x32_bf16(
                    af[m], bfm[n], acc[m][n], 0, 0, 0);
        __syncthreads();
    }

#pragma unroll
    for (int m = 0; m < 4; ++m) {
#pragma unroll
        for (int n = 0; n < 4; ++n) {
            const int col = c0 + wn * 64 + n * 16 + lr;
            const float bval = bias[col];
#pragma unroll
            for (int j = 0; j < 4; ++j) {
                const int row = r0 + wm * 64 + m * 16 + lg * 4 + j;
                const float v = acc[m][n][j] + bval;
                if (OUT_BF16)
                    ((bf16_t*)Cp)[(size_t)row * Ndim + col] = (bf16_t)v;
                else
                    ((float*)Cp)[(size_t)row * Ndim + col] = v;
            }
        }
    }
}

// ---------------------------------------------------------------------------
// Causal flash attention v5 (unchanged from round 6, passed at 47.6 us).
// ---------------------------------------------------------------------------
__global__ __launch_bounds__(256, 4) void attn_kernel(
    const bf16_t* __restrict__ qkv, const bf16_t* __restrict__ vt,
    bf16_t* __restrict__ attn_out)
{
    __shared__ bf16_t Kl[2][4096];
    __shared__ bf16_t Vl[2][4096];
    const int d = blockIdx.x;
    const int r = d >> 8;
    const int u = (d >> 3) & 31;
    int qt = (r & 1) ? (31 - u) : u;
    if (r & 2) qt ^= 16;
    const int bh = (d & 7) + (r << 3);
    const int b = bh >> 4, h = bh & 15;
    const int q0 = qt << 6;
    const int t = threadIdx.x, lane = t & 63, wid = t >> 6;
    const int lr = lane & 15, lg = lane >> 4;
    const int sr = t >> 2, sc16 = (t & 3) << 4;

    const int fragb0 = (lr * 128 + lg * 16) ^ ((lr & 7) << 4);
    const int fragb1 = (lr * 128 + 64 + lg * 16) ^ ((lr & 7) << 4);
    const int stb0   = (sr * 128 + sc16 * 2) ^ ((sr & 7) << 4);
    const int stb1   = (sr * 128 + sc16 * 2 + 16) ^ ((sr & 7) << 4);

    const bf16_t* kp = &qkv[(size_t)(b * SEQLEN + sr) * N3 + EMB + h * 64 + sc16];
    const bf16_t* vp = &vt[(size_t)(bh * 64 + sr) * SEQLEN + sc16];
    const size_t kstep = (size_t)64 * N3;

    const int qg = q0 + wid * 16 + lr;
    bf16x8 qa0, qa1;
    {
        const bf16_t* qb = &qkv[(size_t)(b * SEQLEN + qg) * N3 + h * 64];
        qa0 = *(const bf16x8*)&qb[lg * 8];
        qa1 = *(const bf16x8*)&qb[32 + lg * 8];
    }
    bf16x8 ones;
#pragma unroll
    for (int i = 0; i < 8; ++i) ones[i] = (bf16_t)1.0f;

    f32x4 o[4] = {};
    f32x4 ol = {};
    float m_run = NEG_INF;

    auto stK = [&](char* base, float4 a, float4 c) {
        *(float4*)(base + stb0) = a; *(float4*)(base + stb1) = c;
    };
    auto stV = [&](char* base, float4 a, float4 c) {
        float4 w0 = {a.x, a.y, c.x, c.y};
        float4 w1 = {a.z, a.w, c.z, c.w};
        *(float4*)(base + stb0) = w0; *(float4*)(base + stb1) = w1;
    };

    {
        float4 k0 = *(const float4*)kp, k1 = *(const float4*)(kp + 8);
        float4 v0 = *(const float4*)vp, v1 = *(const float4*)(vp + 8);
        stK((char*)Kl[0], k0, k1);
        stV((char*)Vl[0], v0, v1);
    }
    __syncthreads();
    int cur = 0;
    for (int kt = 0; kt <= qt; ++kt) {
        float4 nk0, nk1, nv0, nv1;
        const bool more = (kt < qt);
        if (more) {
            kp += kstep; vp += 64;
            nk0 = *(const float4*)kp; nk1 = *(const float4*)(kp + 8);
            nv0 = *(const float4*)vp; nv1 = *(const float4*)(vp + 8);
        }

        const char* Kc = (const char*)Kl[cur];
        const char* Vc = (const char*)Vl[cur];

        f32x4 sc[4] = {};
        __builtin_amdgcn_s_setprio(1);
#pragma unroll
        for (int n = 0; n < 4; ++n) {
            bf16x8 kb0 = *(const bf16x8*)(Kc + (fragb0 + n * 2048));
            bf16x8 kb1 = *(const bf16x8*)(Kc + (fragb1 + n * 2048));
            sc[n] = __builtin_amdgcn_mfma_f32_16x16x32_bf16(kb0, qa0, sc[n], 0, 0, 0);
            sc[n] = __builtin_amdgcn_mfma_f32_16x16x32_bf16(kb1, qa1, sc[n], 0, 0, 0);
        }
        __builtin_amdgcn_s_setprio(0);

        if (kt == qt) {
#pragma unroll
            for (int n = 0; n < 4; ++n)
#pragma unroll
                for (int j = 0; j < 4; ++j) {
                    const int kg = kt * 64 + n * 16 + lg * 4 + j;
                    sc[n][j] = (kg <= qg) ? sc[n][j] : NEG_INF;
                }
        }
        float mx[4];
#pragma unroll
        for (int n = 0; n < 4; ++n)
            mx[n] = fmaxf(fmaxf(fmaxf(sc[n][0], sc[n][1]), sc[n][2]), sc[n][3]);
        float pmax = fmaxf(fmaxf(fmaxf(mx[0], mx[1]), mx[2]), mx[3]);

        if (__any(pmax > m_run + 8.f)) {
            float pm = fmaxf(pmax, __shfl_xor(pmax, 16));
            pm = fmaxf(pm, __shfl_xor(pm, 32));
            const float mnew = fmaxf(m_run, pm);
            const float alpha = exp2f(m_run - mnew);
            m_run = mnew;
            float al[4];
#pragma unroll
            for (int j = 0; j < 4; ++j) al[j] = __shfl(alpha, lg * 4 + j);
#pragma unroll
            for (int dn = 0; dn < 4; ++dn)
#pragma unroll
                for (int j = 0; j < 4; ++j) o[dn][j] *= al[j];
#pragma unroll
            for (int j = 0; j < 4; ++j) ol[j] *= al[j];
        }

#pragma unroll
        for (int n = 0; n < 4; ++n)
#pragma unroll
            for (int j = 0; j < 4; ++j) sc[n][j] = exp2f(sc[n][j] - m_run);

        unsigned pk00, pk01, pk10, pk11, pk20, pk21, pk30, pk31;
        asm("v_cvt_pk_bf16_f32 %0, %1, %2" : "=v"(pk00) : "v"(sc[0][0]), "v"(sc[0][1]));
        asm("v_cvt_pk_bf16_f32 %0, %1, %2" : "=v"(pk01) : "v"(sc[0][2]), "v"(sc[0][3]));
        asm("v_cvt_pk_bf16_f32 %0, %1, %2" : "=v"(pk10) : "v"(sc[1][0]), "v"(sc[1][1]));
        asm("v_cvt_pk_bf16_f32 %0, %1, %2" : "=v"(pk11) : "v"(sc[1][2]), "v"(sc[1][3]));
        asm("v_cvt_pk_bf16_f32 %0, %1, %2" : "=v"(pk20) : "v"(sc[2][0]), "v"(sc[2][1]));
        asm("v_cvt_pk_bf16_f32 %0, %1, %2" : "=v"(pk21) : "v"(sc[2][2]), "v"(sc[2][3]));
        asm("v_cvt_pk_bf16_f32 %0, %1, %2" : "=v"(pk30) : "v"(sc[3][0]), "v"(sc[3][1]));
        asm("v_cvt_pk_bf16_f32 %0, %1, %2" : "=v"(pk31) : "v"(sc[3][2]), "v"(sc[3][3]));
        asm("v_permlane32_swap_b32 %0, %1" : "+v"(pk00), "+v"(pk10));
        asm("v_permlane32_swap_b32 %0, %1" : "+v"(pk01), "+v"(pk11));
        asm("v_permlane32_swap_b32 %0, %1" : "+v"(pk20), "+v"(pk30));
        asm("v_permlane32_swap_b32 %0, %1" : "+v"(pk21), "+v"(pk31));
        union UW { unsigned w[4]; bf16x8 v; };
        UW ua, ub;
        ua.w[0] = pk00; ua.w[1] = pk01; ua.w[2] = pk10; ua.w[3] = pk11;
        ub.w[0] = pk20; ub.w[1] = pk21; ub.w[2] = pk30; ub.w[3] = pk31;
        const bf16x8 pa0 = ua.v, pa1 = ub.v;

        __builtin_amdgcn_s_setprio(1);
#pragma unroll
        for (int dn = 0; dn < 4; ++dn) {
            bf16x8 vb0 = *(const bf16x8*)(Vc + (fragb0 + dn * 2048));
            bf16x8 vb1 = *(const bf16x8*)(Vc + (fragb1 + dn * 2048));
            o[dn] = __builtin_amdgcn_mfma_f32_16x16x32_bf16(pa0, vb0, o[dn], 0, 0, 0);
            o[dn] = __builtin_amdgcn_mfma_f32_16x16x32_bf16(pa1, vb1, o[dn], 0, 0, 0);
        }
        ol = __builtin_amdgcn_mfma_f32_16x16x32_bf16(pa0, ones, ol, 0, 0, 0);
        ol = __builtin_amdgcn_mfma_f32_16x16x32_bf16(pa1, ones, ol, 0, 0, 0);
        __builtin_amdgcn_s_setprio(0);

        if (more) {
            stK((char*)Kl[cur ^ 1], nk0, nk1);
            stV((char*)Vl[cur ^ 1], nv0, nv1);
        }
        __syncthreads();
        cur ^= 1;
    }

    float li[4];
#pragma unroll
    for (int j = 0; j < 4; ++j) li[j] = 1.0f / ol[j];
#pragma unroll
    for (int dn = 0; dn < 4; ++dn)
#pragma unroll
        for (int j = 0; j < 4; ++j) {
            const int row = b * SEQLEN + q0 + wid * 16 + lg * 4 + j;
            attn_out[(size_t)row * EMB + h * 64 + dn * 16 + lr] =
                (bf16_t)(o[dn][j] * li[j]);
        }
}

// ---------------------------------------------------------------------------
extern "C" void kernel_launch(void* const* d_in, const int* in_sizes, int n_in,
                              void* d_out, int out_size, void* d_ws, size_t ws_size,
                              hipStream_t stream)
{
    const float* X     = (const float*)d_in[0];
    const float* W_qkv = (const float*)d_in[1];
    const float* b_qkv = (const float*)d_in[2];
    const float* W_out = (const float*)d_in[3];
    const float* b_out = (const float*)d_in[4];
    float* out = (float*)d_out;

    char* ws = (char*)d_ws;
    bf16_t* Wqkv_t = (bf16_t*)ws;                           //  6 MB [3072][1024]
    bf16_t* Wout_t = (bf16_t*)(ws + 6u * 1024 * 1024);      //  2 MB [1024][1024]
    bf16_t* qkv    = (bf16_t*)(ws + 8u * 1024 * 1024);      // 24 MB [4096][3072] (V region unused)
    bf16_t* attn   = (bf16_t*)(ws + 32u * 1024 * 1024);     //  8 MB [4096][1024]
    bf16_t* Xb     = (bf16_t*)(ws + 40u * 1024 * 1024);     //  8 MB [4096][1024]
    bf16_t* Vt_g   = (bf16_t*)(ws + 48u * 1024 * 1024);     //  8 MB [32][64][2048]

    dim3 blk(256);
    transpose_weights<<<dim3(64, 16), blk, 0, stream>>>(W_qkv, W_out, Wqkv_t, Wout_t);
    cvt_f32_bf16<<<4096 * 1024 / (256 * 8), blk, 0, stream>>>(X, Xb, 4096 * 1024);

    // qkv = X @ W_qkv + b_qkv (256^2 8-phase); V col-blocks -> Vt_g transposed
    gemm_8ph_kernel<true, true><<<(4096 / 256) * (N3 / 256), dim3(512), 0, stream>>>(
        Xb, Wqkv_t, b_qkv, (void*)qkv, Vt_g, 1, N3, EMB);

    // causal flash attention -> attn [4096][1024] bf16
    attn_kernel<<<32 * 32, blk, 0, stream>>>(qkv, Vt_g, attn);

    // out = attn @ W_out + b_out  (fp32 out, 128^2 m97 structure)
    gemm_bt_kernel<false><<<(4096 / 128) * (EMB / 128), blk, 0, stream>>>(
        attn, Wout_t, b_out, (void*)out, 4096, EMB, EMB);
}